// Round 2
// baseline (620.822 us; speedup 1.0000x reference)
//
#include <hip/hip_runtime.h>
#include <cstddef>

// SwitchFFN: B=2,S=2048,D=512,E=8,H=2048. T=4096 tokens.
// Round 1: resubmit round-0 f32 implementation (round-0 bench was an
// acquisition timeout — no data).
//   route -> bucket-by-expert -> gathered GEMM1 (relu) -> gathered GEMM2 (scale) -> loss

namespace {

constexpr int T = 4096;
constexpr int D = 512;
constexpr int E = 8;
constexpr int H = 2048;

constexpr int TM = 64;   // tokens per tile
constexpr int TN = 64;   // output cols per tile
constexpr int KB = 32;   // k-step

struct WS {
  int   counts[8];          // per-expert token counts
  int   cursor[8];          // atomic cursors for list build
  float pi8[8];             // softmax row-mean of tokens 0..7
  float rv[T];              // route max prob per token
  int   ridx[T];            // route argmax per token
  int   list[E * T];        // per-expert token lists (stride T)
  float h[(size_t)T * H];   // hidden activations, token-major
};

__global__ void init_k(WS* ws) {
  int i = threadIdx.x;
  if (i < 8) { ws->counts[i] = 0; ws->cursor[i] = 0; }
}

// One wave (64 lanes) per token: logits = x[t] @ Wg + bg, softmax, argmax.
__global__ __launch_bounds__(256) void route_k(const float* __restrict__ x,
                                               const float* __restrict__ Wg,
                                               const float* __restrict__ bg,
                                               WS* __restrict__ ws) {
  int wave = threadIdx.x >> 6;
  int lane = threadIdx.x & 63;
  int t = blockIdx.x * 4 + wave;
  const float* xr = x + (size_t)t * D;
  float acc[8] = {0.f, 0.f, 0.f, 0.f, 0.f, 0.f, 0.f, 0.f};
#pragma unroll
  for (int i = 0; i < 8; ++i) {
    int k = lane + i * 64;
    float xv = xr[k];
    const float4* w = reinterpret_cast<const float4*>(Wg + (size_t)k * 8);
    float4 w0 = w[0], w1 = w[1];
    acc[0] += xv * w0.x; acc[1] += xv * w0.y; acc[2] += xv * w0.z; acc[3] += xv * w0.w;
    acc[4] += xv * w1.x; acc[5] += xv * w1.y; acc[6] += xv * w1.z; acc[7] += xv * w1.w;
  }
#pragma unroll
  for (int e = 0; e < 8; ++e) {
#pragma unroll
    for (int off = 32; off; off >>= 1) acc[e] += __shfl_xor(acc[e], off, 64);
  }
  if (lane == 0) {
    float lg[8], m = -1e30f;
#pragma unroll
    for (int e = 0; e < 8; ++e) { lg[e] = acc[e] + bg[e]; m = fmaxf(m, lg[e]); }
    float p[8], s = 0.f;
#pragma unroll
    for (int e = 0; e < 8; ++e) { p[e] = expf(lg[e] - m); s += p[e]; }
    float inv = 1.0f / s;
    float best = -1.f, psum = 0.f; int bi = 0;
#pragma unroll
    for (int e = 0; e < 8; ++e) {
      float pr = p[e] * inv;
      psum += pr;
      if (pr > best) { best = pr; bi = e; }
    }
    ws->rv[t] = best;
    ws->ridx[t] = bi;
    atomicAdd(&ws->counts[bi], 1);
    if (t < 8) ws->pi8[t] = psum / 8.0f;
  }
}

__global__ void build_k(WS* __restrict__ ws) {
  int t = blockIdx.x * 256 + threadIdx.x;
  if (t >= T) return;
  int e = ws->ridx[t];
  int pos = atomicAdd(&ws->cursor[e], 1);
  ws->list[e * T + pos] = t;
}

// Gathered tiled GEMM: C[t, n] = act( A[t, :] @ Bw[e] + bias[e] )  for t in expert e's list.
// SECOND=false: act = relu, Cout = h.   SECOND=true: act = *rv[t], Cout = out.
template <int KD, int ND, bool SECOND>
__global__ __launch_bounds__(256) void ffn_gemm(const float* __restrict__ A,
                                                const float* __restrict__ Bw,
                                                const float* __restrict__ bias,
                                                float* __restrict__ Cout,
                                                WS* __restrict__ ws) {
  int e = blockIdx.z;
  int cnt = ws->counts[e];
  int m0 = blockIdx.y * TM;
  if (m0 >= cnt) return;
  int n0 = blockIdx.x * TN;
  const float* Bp = Bw + (size_t)e * KD * ND;
  const int* lst = ws->list + e * T;

  __shared__ float As[TM][KB + 4];  // [64][36] — 16B-aligned rows, <=2-way read conflicts
  __shared__ float Bs[KB][TN + 4];  // [32][68]

  int tid = threadIdx.x;
  int tx = tid & 15;   // col group (16 x 4 cols)
  int ty = tid >> 4;   // row group (16 x 4 rows)

  // A staging map: tok = tid/4 (0..63), 8 consecutive k per thread at kc
  int a_tok = tid >> 2;
  int a_kc = (tid & 3) * 8;
  int trowA = m0 + a_tok;
  int tA = lst[trowA < cnt ? trowA : 0];
  const float* Arow = A + (size_t)tA * KD;

  // B staging map: rows b_r and b_r+16, 4 consecutive n at b_c
  int b_r = tid >> 4;
  int b_c = (tid & 15) * 4;

  float acc[4][4] = {};

  for (int k0 = 0; k0 < KD; k0 += KB) {
    float4 av0 = *reinterpret_cast<const float4*>(Arow + k0 + a_kc);
    float4 av1 = *reinterpret_cast<const float4*>(Arow + k0 + a_kc + 4);
    float4 bv0 = *reinterpret_cast<const float4*>(Bp + (size_t)(k0 + b_r) * ND + n0 + b_c);
    float4 bv1 = *reinterpret_cast<const float4*>(Bp + (size_t)(k0 + b_r + 16) * ND + n0 + b_c);
    __syncthreads();  // previous iter's reads done before overwrite
    *reinterpret_cast<float4*>(&As[a_tok][a_kc]) = av0;
    *reinterpret_cast<float4*>(&As[a_tok][a_kc + 4]) = av1;
    *reinterpret_cast<float4*>(&Bs[b_r][b_c]) = bv0;
    *reinterpret_cast<float4*>(&Bs[b_r + 16][b_c]) = bv1;
    __syncthreads();
#pragma unroll
    for (int kk = 0; kk < KB; ++kk) {
      float4 b = *reinterpret_cast<const float4*>(&Bs[kk][tx * 4]);
      float a0 = As[ty * 4 + 0][kk];
      float a1 = As[ty * 4 + 1][kk];
      float a2 = As[ty * 4 + 2][kk];
      float a3 = As[ty * 4 + 3][kk];
      acc[0][0] += a0 * b.x; acc[0][1] += a0 * b.y; acc[0][2] += a0 * b.z; acc[0][3] += a0 * b.w;
      acc[1][0] += a1 * b.x; acc[1][1] += a1 * b.y; acc[1][2] += a1 * b.z; acc[1][3] += a1 * b.w;
      acc[2][0] += a2 * b.x; acc[2][1] += a2 * b.y; acc[2][2] += a2 * b.z; acc[2][3] += a2 * b.w;
      acc[3][0] += a3 * b.x; acc[3][1] += a3 * b.y; acc[3][2] += a3 * b.z; acc[3][3] += a3 * b.w;
    }
  }

  const float4 bv = *reinterpret_cast<const float4*>(bias + (size_t)e * ND + n0 + tx * 4);
#pragma unroll
  for (int i = 0; i < 4; ++i) {
    int trow = m0 + ty * 4 + i;
    if (trow < cnt) {
      int t = lst[trow];
      float4 r;
      r.x = acc[i][0] + bv.x;
      r.y = acc[i][1] + bv.y;
      r.z = acc[i][2] + bv.z;
      r.w = acc[i][3] + bv.w;
      if (SECOND) {
        float rvv = ws->rv[t];
        r.x *= rvv; r.y *= rvv; r.z *= rvv; r.w *= rvv;
      } else {
        r.x = fmaxf(r.x, 0.f); r.y = fmaxf(r.y, 0.f);
        r.z = fmaxf(r.z, 0.f); r.w = fmaxf(r.w, 0.f);
      }
      *reinterpret_cast<float4*>(Cout + (size_t)t * ND + n0 + tx * 4) = r;
    }
  }
}

__global__ void loss_k(const WS* __restrict__ ws, float* __restrict__ out) {
  if (threadIdx.x == 0 && blockIdx.x == 0) {
    float s = 0.f;
#pragma unroll
    for (int i = 0; i < 8; ++i) s += ((float)ws->counts[i] / (float)T) * ws->pi8[i];
    out[(size_t)T * D] = 0.01f * (float)E * s;
  }
}

}  // namespace

extern "C" void kernel_launch(void* const* d_in, const int* in_sizes, int n_in,
                              void* d_out, int out_size, void* d_ws, size_t ws_size,
                              hipStream_t stream) {
  const float* x  = (const float*)d_in[0];
  const float* Wg = (const float*)d_in[1];
  const float* bg = (const float*)d_in[2];
  const float* W1 = (const float*)d_in[3];
  const float* b1 = (const float*)d_in[4];
  const float* W2 = (const float*)d_in[5];
  const float* b2 = (const float*)d_in[6];
  float* out = (float*)d_out;
  WS* ws = (WS*)d_ws;
  float* hbuf = (float*)((char*)d_ws + offsetof(WS, h));

  hipLaunchKernelGGL(init_k, dim3(1), dim3(64), 0, stream, ws);
  hipLaunchKernelGGL(route_k, dim3(T / 4), dim3(256), 0, stream, x, Wg, bg, ws);
  hipLaunchKernelGGL(build_k, dim3(T / 256), dim3(256), 0, stream, ws);
  hipLaunchKernelGGL((ffn_gemm<D, H, false>), dim3(H / TN, T / TM, E), dim3(256), 0, stream,
                     x, W1, b1, hbuf, ws);
  hipLaunchKernelGGL((ffn_gemm<H, D, true>), dim3(D / TN, T / TM, E), dim3(256), 0, stream,
                     hbuf, W2, b2, out, ws);
  hipLaunchKernelGGL(loss_k, dim3(1), dim3(1), 0, stream, ws, out);
}

// Round 4
// 260.189 us; speedup vs baseline: 2.3860x; 2.3860x over previous
//
#include <hip/hip_runtime.h>
#include <hip/hip_bf16.h>
#include <cstddef>
#include <cstdint>

// SwitchFFN: B=2,S=2048,D=512,E=8,H=2048. T=4096 tokens.
// Round 3 resubmit (round-3 bench was an acquisition timeout — no data).
// bf16 MFMA GEMMs (16x16x32), f32 accumulate.
//   route -> bucket -> prefix -> cvt(x,W1^T,W2^T to bf16) ->
//   mfma GEMM1 (gathered A, relu, compact bf16 h) ->
//   mfma GEMM2 (contiguous A, scatter f32 out * rv) -> loss

namespace {

constexpr int T = 4096;
constexpr int D = 512;
constexpr int E = 8;
constexpr int H = 2048;

typedef __attribute__((ext_vector_type(8))) short short8;
typedef __attribute__((ext_vector_type(4))) float f32x4;

struct WS {
  int   counts[8];
  int   cursor[8];
  int   base[8];
  float pi8[8];
  float rv[T];
  int   ridx[T];
  int   list[E * T];
};

constexpr size_t HDR     = (sizeof(WS) + 255) & ~size_t(255);
constexpr size_t XB_OFF  = HDR;                                      // bf16 x   [T][D]
constexpr size_t WT1_OFF = XB_OFF  + 2 * (size_t)T * D;              // bf16 W1^T [E][H][D]
constexpr size_t WT2_OFF = WT1_OFF + 2 * (size_t)E * H * D;          // bf16 W2^T [E][D][H]
constexpr size_t HB_OFF  = WT2_OFF + 2 * (size_t)E * D * H;          // bf16 h (compact) [T][H]

#define GLD16(g, l)                                                       \
  __builtin_amdgcn_global_load_lds(                                       \
      (const __attribute__((address_space(1))) void*)(g),                 \
      (__attribute__((address_space(3))) void*)(l), 16, 0, 0)

__global__ void init_k(WS* ws) {
  int i = threadIdx.x;
  if (i < 8) { ws->counts[i] = 0; ws->cursor[i] = 0; }
}

// One wave per token: logits = x[t] @ Wg + bg, softmax, argmax. (f32)
__global__ __launch_bounds__(256) void route_k(const float* __restrict__ x,
                                               const float* __restrict__ Wg,
                                               const float* __restrict__ bg,
                                               WS* __restrict__ ws) {
  int wave = threadIdx.x >> 6;
  int lane = threadIdx.x & 63;
  int t = blockIdx.x * 4 + wave;
  const float* xr = x + (size_t)t * D;
  float acc[8] = {0.f, 0.f, 0.f, 0.f, 0.f, 0.f, 0.f, 0.f};
#pragma unroll
  for (int i = 0; i < 8; ++i) {
    int k = lane + i * 64;
    float xv = xr[k];
    const float4* w = reinterpret_cast<const float4*>(Wg + (size_t)k * 8);
    float4 w0 = w[0], w1 = w[1];
    acc[0] += xv * w0.x; acc[1] += xv * w0.y; acc[2] += xv * w0.z; acc[3] += xv * w0.w;
    acc[4] += xv * w1.x; acc[5] += xv * w1.y; acc[6] += xv * w1.z; acc[7] += xv * w1.w;
  }
#pragma unroll
  for (int e = 0; e < 8; ++e) {
#pragma unroll
    for (int off = 32; off; off >>= 1) acc[e] += __shfl_xor(acc[e], off, 64);
  }
  if (lane == 0) {
    float lg[8], m = -1e30f;
#pragma unroll
    for (int e = 0; e < 8; ++e) { lg[e] = acc[e] + bg[e]; m = fmaxf(m, lg[e]); }
    float p[8], s = 0.f;
#pragma unroll
    for (int e = 0; e < 8; ++e) { p[e] = expf(lg[e] - m); s += p[e]; }
    float inv = 1.0f / s;
    float best = -1.f, psum = 0.f; int bi = 0;
#pragma unroll
    for (int e = 0; e < 8; ++e) {
      float pr = p[e] * inv;
      psum += pr;
      if (pr > best) { best = pr; bi = e; }
    }
    ws->rv[t] = best;
    ws->ridx[t] = bi;
    atomicAdd(&ws->counts[bi], 1);
    if (t < 8) ws->pi8[t] = psum / 8.0f;
  }
}

__global__ void build_k(WS* __restrict__ ws) {
  int t = blockIdx.x * 256 + threadIdx.x;
  if (t >= T) return;
  int e = ws->ridx[t];
  int pos = atomicAdd(&ws->cursor[e], 1);
  ws->list[e * T + pos] = t;
}

__global__ void prefix_k(WS* __restrict__ ws) {
  if (threadIdx.x == 0) {
    int b = 0;
#pragma unroll
    for (int e = 0; e < 8; ++e) { ws->base[e] = b; b += ws->counts[e]; }
  }
}

// x (f32) -> xb (bf16), 8 elements/thread
__global__ __launch_bounds__(256) void cvt_x(const float* __restrict__ x,
                                             __hip_bfloat16* __restrict__ xb) {
  size_t i = (size_t)blockIdx.x * 256 + threadIdx.x;
  const float4* p = reinterpret_cast<const float4*>(x) + i * 2;
  float4 a = p[0], b = p[1];
  alignas(16) __hip_bfloat16 o[8];
  o[0] = __float2bfloat16(a.x); o[1] = __float2bfloat16(a.y);
  o[2] = __float2bfloat16(a.z); o[3] = __float2bfloat16(a.w);
  o[4] = __float2bfloat16(b.x); o[5] = __float2bfloat16(b.y);
  o[6] = __float2bfloat16(b.z); o[7] = __float2bfloat16(b.w);
  *reinterpret_cast<int4*>(xb + i * 8) = *reinterpret_cast<int4*>(o);
}

// in [E][K][N] f32 -> out [E][N][K] bf16 (64x64 LDS-tiled transpose+convert)
template <int K, int N>
__global__ __launch_bounds__(256) void cvt_t(const float* __restrict__ in,
                                             __hip_bfloat16* __restrict__ outp) {
  const int e = blockIdx.z;
  in   += (size_t)e * K * N;
  outp += (size_t)e * K * N;
  const int k0 = blockIdx.y * 64, n0 = blockIdx.x * 64;
  __shared__ __hip_bfloat16 tile[64][72];
  const int r = threadIdx.x >> 4, c = (threadIdx.x & 15) * 4;
#pragma unroll
  for (int rr = 0; rr < 4; ++rr) {
    float4 v = *reinterpret_cast<const float4*>(in + (size_t)(k0 + r + rr * 16) * N + n0 + c);
    tile[r + rr * 16][c + 0] = __float2bfloat16(v.x);
    tile[r + rr * 16][c + 1] = __float2bfloat16(v.y);
    tile[r + rr * 16][c + 2] = __float2bfloat16(v.z);
    tile[r + rr * 16][c + 3] = __float2bfloat16(v.w);
  }
  __syncthreads();
  const int n = threadIdx.x >> 2, ch = threadIdx.x & 3;
  alignas(16) __hip_bfloat16 o[16];
#pragma unroll
  for (int i = 0; i < 16; ++i) o[i] = tile[ch * 16 + i][n];
  __hip_bfloat16* dst = outp + (size_t)(n0 + n) * K + k0 + ch * 16;
  reinterpret_cast<int4*>(dst)[0] = reinterpret_cast<int4*>(o)[0];
  reinterpret_cast<int4*>(dst)[1] = reinterpret_cast<int4*>(o)[1];
}

// MFMA GEMM. BM=128, BK=64. A rows gathered (GEMM1) or compact (GEMM2).
// LDS tiles [rows][64] bf16 (128B rows, 8x16B chunks) with XOR chunk swizzle:
// chunk c of row r holds source chunk (c ^ (r&7)); reader applies same XOR.
template <int K, int BN, int WR, int WC, bool SECOND>
__global__ __launch_bounds__(256) void mgemm(const __hip_bfloat16* __restrict__ Ag,
                                             const __hip_bfloat16* __restrict__ Wt,
                                             const float* __restrict__ bias,
                                             __hip_bfloat16* __restrict__ hb,
                                             float* __restrict__ outp,
                                             WS* __restrict__ ws) {
  constexpr int BM = 128;
  constexpr int BK = 64;
  constexpr int NDIM = SECOND ? D : H;      // full N of this GEMM
  constexpr int MS = BM / WR, NS = BN / WC; // per-wave output span
  constexpr int MF = MS / 16, NF = NS / 16;
  constexpr int ACALLS = BM / 32;           // 4KB per global_load_lds round
  constexpr int BCALLS = BN / 32;

  const int e = blockIdx.z;
  const int cnt = ws->counts[e];
  const int m0 = blockIdx.y * BM;
  if (m0 >= cnt) return;
  const int n0 = blockIdx.x * BN;
  const int bas = ws->base[e];
  const int* lst = ws->list + e * T;

  const int tid = threadIdx.x, lane = tid & 63, wave = tid >> 6;
  const int wr = wave / WC, wc = wave % WC;
  const int wrow = wr * MS, wcol = wc * NS;

  __shared__ unsigned char As[BM * 128];
  __shared__ unsigned char Bs[BN * 128];

  // staging source pointers (per thread, per 4KB call); row clamp for tails
  const int srow = tid >> 3;
  const int sj = tid & 7;
  const unsigned short* aptr[ACALLS];
#pragma unroll
  for (int q = 0; q < ACALLS; ++q) {
    int row = q * 32 + srow;
    int jj = sj ^ (row & 7);
    int mrow = m0 + row; if (mrow > cnt - 1) mrow = cnt - 1;
    int arow = SECOND ? (bas + mrow) : lst[mrow];
    aptr[q] = reinterpret_cast<const unsigned short*>(Ag) + (size_t)arow * K + jj * 8;
  }
  const unsigned short* bptr[BCALLS];
#pragma unroll
  for (int q = 0; q < BCALLS; ++q) {
    int row = q * 32 + srow;
    int jj = sj ^ (row & 7);
    bptr[q] = reinterpret_cast<const unsigned short*>(Wt) +
              ((size_t)e * NDIM + n0 + row) * K + jj * 8;
  }

  f32x4 acc[MF][NF] = {};

  for (int k0 = 0; k0 < K; k0 += BK) {
#pragma unroll
    for (int q = 0; q < ACALLS; ++q) GLD16(aptr[q] + k0, As + q * 4096 + (wave << 10));
#pragma unroll
    for (int q = 0; q < BCALLS; ++q) GLD16(bptr[q] + k0, Bs + q * 4096 + (wave << 10));
    __syncthreads();  // compiler drains vmcnt before barrier
#pragma unroll
    for (int s = 0; s < 2; ++s) {
      const int jA = s * 4 + (lane >> 4);
      short8 af[MF], bfr[NF];
#pragma unroll
      for (int m = 0; m < MF; ++m) {
        int row = wrow + m * 16 + (lane & 15);
        af[m] = *reinterpret_cast<const short8*>(As + row * 128 + ((jA ^ (row & 7)) << 4));
      }
#pragma unroll
      for (int n = 0; n < NF; ++n) {
        int row = wcol + n * 16 + (lane & 15);
        bfr[n] = *reinterpret_cast<const short8*>(Bs + row * 128 + ((jA ^ (row & 7)) << 4));
      }
#pragma unroll
      for (int m = 0; m < MF; ++m)
#pragma unroll
        for (int n = 0; n < NF; ++n)
          acc[m][n] = __builtin_amdgcn_mfma_f32_16x16x32_bf16(af[m], bfr[n], acc[m][n], 0, 0, 0);
    }
    __syncthreads();  // reads done before next stage overwrites
  }

  // epilogue — C/D map: col = lane&15, row = (lane>>4)*4 + i
  const int colbase = n0 + wcol + (lane & 15);
  float bia[NF];
#pragma unroll
  for (int n = 0; n < NF; ++n) bia[n] = bias[(size_t)e * NDIM + colbase + n * 16];
#pragma unroll
  for (int m = 0; m < MF; ++m) {
    const int rloc = wrow + m * 16 + ((lane >> 4) << 2);
#pragma unroll
    for (int i = 0; i < 4; ++i) {
      const int r = m0 + rloc + i;
      if (r < cnt) {
        if (!SECOND) {
          __hip_bfloat16* hrow = hb + (size_t)(bas + r) * H + colbase;
#pragma unroll
          for (int n = 0; n < NF; ++n)
            hrow[n * 16] = __float2bfloat16(fmaxf(acc[m][n][i] + bia[n], 0.f));
        } else {
          const int t = lst[r];
          const float s = ws->rv[t];
          float* orow = outp + (size_t)t * D + colbase;
#pragma unroll
          for (int n = 0; n < NF; ++n)
            orow[n * 16] = (acc[m][n][i] + bia[n]) * s;
        }
      }
    }
  }
}

__global__ void loss_k(const WS* __restrict__ ws, float* __restrict__ out) {
  if (threadIdx.x == 0 && blockIdx.x == 0) {
    float s = 0.f;
#pragma unroll
    for (int i = 0; i < 8; ++i) s += ((float)ws->counts[i] / (float)T) * ws->pi8[i];
    out[(size_t)T * D] = 0.01f * (float)E * s;
  }
}

}  // namespace

extern "C" void kernel_launch(void* const* d_in, const int* in_sizes, int n_in,
                              void* d_out, int out_size, void* d_ws, size_t ws_size,
                              hipStream_t stream) {
  const float* x  = (const float*)d_in[0];
  const float* Wg = (const float*)d_in[1];
  const float* bg = (const float*)d_in[2];
  const float* W1 = (const float*)d_in[3];
  const float* b1 = (const float*)d_in[4];
  const float* W2 = (const float*)d_in[5];
  const float* b2 = (const float*)d_in[6];
  float* out = (float*)d_out;
  WS* ws = (WS*)d_ws;
  char* wsb = (char*)d_ws;
  __hip_bfloat16* xb  = (__hip_bfloat16*)(wsb + XB_OFF);
  __hip_bfloat16* wt1 = (__hip_bfloat16*)(wsb + WT1_OFF);
  __hip_bfloat16* wt2 = (__hip_bfloat16*)(wsb + WT2_OFF);
  __hip_bfloat16* hbp = (__hip_bfloat16*)(wsb + HB_OFF);

  hipLaunchKernelGGL(init_k, dim3(1), dim3(64), 0, stream, ws);
  hipLaunchKernelGGL(route_k, dim3(T / 4), dim3(256), 0, stream, x, Wg, bg, ws);
  hipLaunchKernelGGL(build_k, dim3(T / 256), dim3(256), 0, stream, ws);
  hipLaunchKernelGGL(prefix_k, dim3(1), dim3(64), 0, stream, ws);
  hipLaunchKernelGGL(cvt_x, dim3((T * D) / (256 * 8)), dim3(256), 0, stream, x, xb);
  hipLaunchKernelGGL((cvt_t<D, H>), dim3(H / 64, D / 64, E), dim3(256), 0, stream, W1, wt1);
  hipLaunchKernelGGL((cvt_t<H, D>), dim3(D / 64, H / 64, E), dim3(256), 0, stream, W2, wt2);
  hipLaunchKernelGGL((mgemm<D, 128, 2, 2, false>), dim3(H / 128, 32, E), dim3(256), 0, stream,
                     xb, wt1, b1, hbp, nullptr, ws);
  hipLaunchKernelGGL((mgemm<H, 64, 4, 1, true>), dim3(D / 64, 32, E), dim3(256), 0, stream,
                     hbp, wt2, b2, nullptr, out, ws);
  hipLaunchKernelGGL(loss_k, dim3(1), dim3(1), 0, stream, ws, out);
}